// Round 18
// baseline (375.548 us; speedup 1.0000x reference)
//
#include <hip/hip_runtime.h>
#include <hip/hip_bf16.h>
#include <math.h>

// Problem constants
#define NB    2048          // B
#define ACT   14
#define NC    128           // C
#define NH    32            // H
#define NNODE (NB*ACT)      // 28672
#define NEDGE (NB*ACT*ACT)  // 401408
#define NPAIR (NB*ACT*ACT)  // 401408 output rows (b, 196)
#define BCAP  64            // bucket capacity per node

// DIAGNOSTIC ROUND: idempotent kernels repeat internally to amplify their
// dispatch duration past the harness-fill top-5 cutoff (~46us).
// True cost = dispatch_dur / REP_*.
#define REP_G1 24
#define REP_GA 8
#define REP_G2 24
#define REP_PR 12

typedef __attribute__((ext_vector_type(8))) short bf16x8;
typedef __attribute__((ext_vector_type(4))) float f32x4;

__device__ __forceinline__ unsigned short f2bf(float f)
{
    unsigned u = __float_as_uint(f);
    return (unsigned short)((u + 0x7fff + ((u >> 16) & 1)) >> 16);
}
__device__ __forceinline__ float bf2f(unsigned short h)
{
    return __uint_as_float(((unsigned)h) << 16);
}
__device__ __forceinline__ float bfl(unsigned v) { return __uint_as_float(v << 16); }
__device__ __forceinline__ float bfh(unsigned v) { return __uint_as_float(v & 0xffff0000u); }

// ---------------------------------------------------------------------------
// init: cnt=0, dummy y row=0, pack convW^T bf16, pack W1 hi/lo bf16,
// pack W2 col-major bf16
// ---------------------------------------------------------------------------
__global__ __launch_bounds__(256) void init_misc(
    int* __restrict__ cnt, unsigned short* __restrict__ ydummy,
    const float* __restrict__ convW, unsigned short* __restrict__ convWt,
    const float* __restrict__ W1,
    unsigned short* __restrict__ Whi, unsigned short* __restrict__ Wlo,
    const float* __restrict__ W2, unsigned short* __restrict__ W2cm)
{
    int idx = blockIdx.x * 256 + threadIdx.x;          // 0 .. 28671
    if (idx < NNODE) cnt[idx] = 0;
    if (idx < 128) ydummy[idx] = 0;
    if (idx < 128 * 128) {
        int c = idx >> 7, k = idx & 127;
        convWt[idx] = f2bf(convW[k * 128 + c]);
    }
    if (idx < 64 * 128) {
        int c = idx >> 7, k = idx & 127;
        float w = (c < 32) ? W1[k * 32 + c] : W1[(128 + k) * 32 + (c - 32)];
        unsigned short h = f2bf(w);
        Whi[idx] = h;
        Wlo[idx] = f2bf(w - bf2f(h));
    }
    if (idx < 1024) {
        int c = idx >> 5, kk = idx & 31;
        W2cm[c * 32 + kk] = f2bf(W2[kk * 32 + c]);
    }
}

// ---------------------------------------------------------------------------
// bucket fill (NOT amplified - atomics are not idempotent)
// ---------------------------------------------------------------------------
__global__ void bucket_fill(const int* __restrict__ src, const int* __restrict__ dst,
                            int* __restrict__ cnt, int* __restrict__ bucket)
{
    int e = blockIdx.x * blockDim.x + threadIdx.x;
    if (e < NEDGE) {
        int d = dst[e];
        int slot = atomicAdd(&cnt[d], 1);
        if (slot < BCAP) bucket[(size_t)d * BCAP + slot] = src[e];
    }
}

// ---------------------------------------------------------------------------
// GEMM1 (MFMA, split-precision A), amplified x24
// ---------------------------------------------------------------------------
__global__ __launch_bounds__(256) void gemm1_mfma(
    const float* __restrict__ A, const unsigned short* __restrict__ Bt,
    const int* __restrict__ cnt, unsigned short* __restrict__ y)
{
    __shared__ unsigned short Ah[128 * 128];   // 32 KB
    __shared__ unsigned short Alo[128 * 128];  // 32 KB
    __shared__ unsigned short Bl[128 * 128];   // 32 KB
    const int tid  = threadIdx.x;
    const int row0 = blockIdx.x * 128;

    for (int rep = 0; rep < REP_G1; ++rep) {
#pragma unroll
    for (int it = 0; it < 16; ++it) {
        int idx = tid + it * 256;
        int r = idx >> 5;
        int c = (idx & 31) << 2;
        float4 v = ((const float4*)(A + (size_t)(row0 + r) * 128))[idx & 31];
        ushort4 h, l;
        h.x = f2bf(v.x); l.x = f2bf(v.x - bf2f(h.x));
        h.y = f2bf(v.y); l.y = f2bf(v.y - bf2f(h.y));
        h.z = f2bf(v.z); l.z = f2bf(v.z - bf2f(h.z));
        h.w = f2bf(v.w); l.w = f2bf(v.w - bf2f(h.w));
        int byte = (r * 256 + c * 2) ^ ((r & 7) << 4);
        *(ushort4*)((char*)Ah  + byte) = h;
        *(ushort4*)((char*)Alo + byte) = l;
    }
#pragma unroll
    for (int it = 0; it < 8; ++it) {
        int idx = tid + it * 256;
        int cc = idx >> 4;
        int kk = (idx & 15) << 3;
        bf16x8 v = *((const bf16x8*)(Bt + cc * 128 + kk));
        int byte = (cc * 256 + kk * 2) ^ ((cc & 7) << 4);
        *(bf16x8*)((char*)Bl + byte) = v;
    }
    __syncthreads();

    const int wv = tid >> 6, lane = tid & 63;
    const int lr = lane & 15, kb = lane >> 4;
    const int col0 = wv * 32;

    f32x4 acc0[8], acc1[8];
#pragma unroll
    for (int mt = 0; mt < 8; ++mt) {
        acc0[mt] = (f32x4){0.f, 0.f, 0.f, 0.f};
        acc1[mt] = (f32x4){0.f, 0.f, 0.f, 0.f};
    }

#pragma unroll
    for (int ks = 0; ks < 4; ++ks) {
        const int kbyte = (ks * 32 + kb * 8) * 2;
        int cb0 = ((col0 + lr) * 256 + kbyte) ^ (((col0 + lr) & 7) << 4);
        int cb1 = ((col0 + 16 + lr) * 256 + kbyte) ^ (((col0 + 16 + lr) & 7) << 4);
        bf16x8 b0 = *(const bf16x8*)((char*)Bl + cb0);
        bf16x8 b1 = *(const bf16x8*)((char*)Bl + cb1);
#pragma unroll
        for (int mt = 0; mt < 8; ++mt) {
            int rr = mt * 16 + lr;
            int ab = (rr * 256 + kbyte) ^ ((rr & 7) << 4);
            bf16x8 ah = *(const bf16x8*)((char*)Ah  + ab);
            bf16x8 al = *(const bf16x8*)((char*)Alo + ab);
            acc0[mt] = __builtin_amdgcn_mfma_f32_16x16x32_bf16(ah, b0, acc0[mt], 0, 0, 0);
            acc0[mt] = __builtin_amdgcn_mfma_f32_16x16x32_bf16(al, b0, acc0[mt], 0, 0, 0);
            acc1[mt] = __builtin_amdgcn_mfma_f32_16x16x32_bf16(ah, b1, acc1[mt], 0, 0, 0);
            acc1[mt] = __builtin_amdgcn_mfma_f32_16x16x32_bf16(al, b1, acc1[mt], 0, 0, 0);
        }
    }

#pragma unroll
    for (int mt = 0; mt < 8; ++mt) {
#pragma unroll
        for (int t = 0; t < 4; ++t) {
            int grow = row0 + mt * 16 + kb * 4 + t;
            float s = rsqrtf((float)cnt[grow] + 1.0f);
            y[(size_t)grow * 128 + col0 + lr]      = f2bf(acc0[mt][t] * s);
            y[(size_t)grow * 128 + col0 + 16 + lr] = f2bf(acc1[mt][t] * s);
        }
    }
    __syncthreads();
    asm volatile("" ::: "memory");
    }   // rep
}

// ---------------------------------------------------------------------------
// GEMM2 (MFMA split-precision), amplified x24
// ---------------------------------------------------------------------------
__global__ __launch_bounds__(256) void gemm2_mfma(
    const float* __restrict__ X, const unsigned short* __restrict__ Whi,
    const unsigned short* __restrict__ Wlo, float* __restrict__ U)
{
    __shared__ unsigned short Ah[64 * 128];
    __shared__ unsigned short Alo[64 * 128];
    __shared__ unsigned short Bh[64 * 128];
    __shared__ unsigned short Blo[64 * 128];
    const int tid  = threadIdx.x;
    const int row0 = blockIdx.x * 64;

    for (int rep = 0; rep < REP_G2; ++rep) {
#pragma unroll
    for (int it = 0; it < 8; ++it) {
        int idx = tid + it * 256;
        int r = idx >> 5;
        int c = (idx & 31) << 2;
        float4 v = ((const float4*)(X + (size_t)(row0 + r) * 128))[idx & 31];
        ushort4 h, l;
        h.x = f2bf(v.x); l.x = f2bf(v.x - bf2f(h.x));
        h.y = f2bf(v.y); l.y = f2bf(v.y - bf2f(h.y));
        h.z = f2bf(v.z); l.z = f2bf(v.z - bf2f(h.z));
        h.w = f2bf(v.w); l.w = f2bf(v.w - bf2f(h.w));
        int byte = (r * 256 + c * 2) ^ ((r & 7) << 4);
        *(ushort4*)((char*)Ah  + byte) = h;
        *(ushort4*)((char*)Alo + byte) = l;
    }
#pragma unroll
    for (int it = 0; it < 4; ++it) {
        int idx = tid + it * 256;
        int cc = idx >> 4;
        int kk = (idx & 15) << 3;
        int byte = (cc * 256 + kk * 2) ^ ((cc & 7) << 4);
        *(bf16x8*)((char*)Bh  + byte) = *((const bf16x8*)(Whi + cc * 128 + kk));
        *(bf16x8*)((char*)Blo + byte) = *((const bf16x8*)(Wlo + cc * 128 + kk));
    }
    __syncthreads();

    const int wv = tid >> 6, lane = tid & 63;
    const int lr = lane & 15, kb = lane >> 4;
    const int col0 = wv * 16;

    f32x4 acc[4];
#pragma unroll
    for (int mt = 0; mt < 4; ++mt) acc[mt] = (f32x4){0.f, 0.f, 0.f, 0.f};

#pragma unroll
    for (int ks = 0; ks < 4; ++ks) {
        const int kbyte = (ks * 32 + kb * 8) * 2;
        int cb = ((col0 + lr) * 256 + kbyte) ^ (((col0 + lr) & 7) << 4);
        bf16x8 bh = *(const bf16x8*)((char*)Bh  + cb);
        bf16x8 bl = *(const bf16x8*)((char*)Blo + cb);
#pragma unroll
        for (int mt = 0; mt < 4; ++mt) {
            int rr = mt * 16 + lr;
            int ab = (rr * 256 + kbyte) ^ ((rr & 7) << 4);
            bf16x8 ah = *(const bf16x8*)((char*)Ah  + ab);
            bf16x8 al = *(const bf16x8*)((char*)Alo + ab);
            acc[mt] = __builtin_amdgcn_mfma_f32_16x16x32_bf16(ah, bh, acc[mt], 0, 0, 0);
            acc[mt] = __builtin_amdgcn_mfma_f32_16x16x32_bf16(al, bh, acc[mt], 0, 0, 0);
            acc[mt] = __builtin_amdgcn_mfma_f32_16x16x32_bf16(ah, bl, acc[mt], 0, 0, 0);
        }
    }

#pragma unroll
    for (int mt = 0; mt < 4; ++mt) {
#pragma unroll
        for (int t = 0; t < 4; ++t) {
            int grow = row0 + mt * 16 + kb * 4 + t;
            U[(size_t)grow * 64 + col0 + lr] = acc[mt][t];
        }
    }
    __syncthreads();
    asm volatile("" ::: "memory");
    }   // rep
}

// ---------------------------------------------------------------------------
// gather (R14 shfl version), amplified x8
// ---------------------------------------------------------------------------
__global__ __launch_bounds__(256) void gather_agg(
    const int* __restrict__ bucket, const int* __restrict__ cnt,
    const unsigned short* __restrict__ y, const float* __restrict__ bias,
    const float* __restrict__ state, float* __restrict__ xout)
{
    const int lane = threadIdx.x & 31;
    const int d = (blockIdx.x * 256 + threadIdx.x) >> 5;
    if (d >= NNODE) return;

    const int c_true = cnt[d];
    const int c = c_true < BCAP ? c_true : BCAP;
    const int* brow = bucket + (size_t)d * BCAP;
    const float dv = rsqrtf((float)c_true + 1.0f);
    float4 b  = ((const float4*)bias)[lane];

    for (int rep = 0; rep < REP_GA; ++rep) {
        uint2 sv0 = ((const uint2*)(y + (size_t)d * NC))[lane];
        float4 acc;
        acc.x = bfl(sv0.x); acc.y = bfh(sv0.x);
        acc.z = bfl(sv0.y); acc.w = bfh(sv0.y);

        for (int base = 0; base < c; base += 32) {
            int rem = c - base;
            int m = rem < 32 ? rem : 32;
            int sv = (lane < m) ? brow[base + lane] : NNODE;
            int mm = (m + 3) & ~3;
            for (int j = 0; j < mm; j += 4) {
                int s0 = __shfl(sv, j + 0, 32);
                int s1 = __shfl(sv, j + 1, 32);
                int s2 = __shfl(sv, j + 2, 32);
                int s3 = __shfl(sv, j + 3, 32);
                uint2 a0 = ((const uint2*)(y + (size_t)s0 * NC))[lane];
                uint2 a1 = ((const uint2*)(y + (size_t)s1 * NC))[lane];
                uint2 a2 = ((const uint2*)(y + (size_t)s2 * NC))[lane];
                uint2 a3 = ((const uint2*)(y + (size_t)s3 * NC))[lane];
                acc.x += bfl(a0.x) + bfl(a1.x) + bfl(a2.x) + bfl(a3.x);
                acc.y += bfh(a0.x) + bfh(a1.x) + bfh(a2.x) + bfh(a3.x);
                acc.z += bfl(a0.y) + bfl(a1.y) + bfl(a2.y) + bfl(a3.y);
                acc.w += bfh(a0.y) + bfh(a1.y) + bfh(a2.y) + bfh(a3.y);
            }
        }

        float4 st = ((const float4*)(state + (size_t)d * NC))[lane];
        float4 r;
        r.x = fmaxf(acc.x * dv + b.x, 0.f) + st.x;
        r.y = fmaxf(acc.y * dv + b.y, 0.f) + st.y;
        r.z = fmaxf(acc.z * dv + b.z, 0.f) + st.z;
        r.w = fmaxf(acc.w * dv + b.w, 0.f) + st.w;
        ((float4*)(xout + (size_t)d * NC))[lane] = r;
        asm volatile("" ::: "memory");
    }
}

// ---------------------------------------------------------------------------
// pairs v6, amplified x12
// ---------------------------------------------------------------------------
__device__ __forceinline__ float softplusf(float z)
{
    return z > 0.f ? z + log1pf(expf(-z)) : log1pf(expf(z));
}
__device__ __forceinline__ float leakyf(float z)
{
    return z > 0.f ? z : 0.01f * z;
}

__global__ __launch_bounds__(256) void pairs_mfma5_kernel(
    const float* __restrict__ uv, const unsigned short* __restrict__ W2cm,
    const float* __restrict__ b1, const float* __restrict__ b2,
    const float* __restrict__ muW, const float* __restrict__ mu_b,
    const float* __restrict__ sigW, const float* __restrict__ sig_b,
    float* __restrict__ out)
{
    __shared__ float uvs[42 * 68];
    __shared__ float h2s[4][64 * 33];
    const int tid  = threadIdx.x;
    const int wv   = tid >> 6;
    const int lane = tid & 63;
    const int lr   = lane & 15;
    const int kb   = lane >> 4;
    const int k0   = kb * 8;
    const int b0 = (blockIdx.x * 256) / 196;
    const int nodebase = b0 * ACT;

    bf16x8 bfr0 = *((const bf16x8*)(W2cm + (size_t)lr * 32 + k0));
    bf16x8 bfr1 = *((const bf16x8*)(W2cm + (size_t)(16 + lr) * 32 + k0));
    float4 c0 = *((const float4*)(b1 + k0));
    float4 c1 = *((const float4*)(b1 + k0 + 4));

    for (int rep = 0; rep < REP_PR; ++rep) {
#pragma unroll
    for (int it = 0; it < 3; ++it) {
        int c = tid + it * 256;
        if (c < 42 * 16) {
            int r = c >> 4, q = c & 15;
            if (nodebase + r < NNODE) {
                float4 v = ((const float4*)(uv + (size_t)(nodebase + r) * 64))[q];
                *((float4*)&uvs[r * 68 + q * 4]) = v;
            }
        }
    }
    __syncthreads();

    float* h2w = h2s[wv];
#pragma unroll
    for (int tt = 0; tt < 4; ++tt) {
        const int g = blockIdx.x * 256 + wv * 64 + tt * 16 + lr;
        const int b = g / 196;
        const int p = g - b * 196;
        const int i = p / 14;
        const int j = p - i * 14;
        const float* up = &uvs[((b - b0) * ACT + i) * 68 + k0];
        const float* vp = &uvs[((b - b0) * ACT + j) * 68 + 32 + k0];
        float4 u0 = *((const float4*)up);
        float4 u1 = *((const float4*)(up + 4));
        float4 v0 = *((const float4*)vp);
        float4 v1 = *((const float4*)(vp + 4));

        bf16x8 a;
        a[0] = (short)f2bf(leakyf(u0.x + v0.x + c0.x));
        a[1] = (short)f2bf(leakyf(u0.y + v0.y + c0.y));
        a[2] = (short)f2bf(leakyf(u0.z + v0.z + c0.z));
        a[3] = (short)f2bf(leakyf(u0.w + v0.w + c0.w));
        a[4] = (short)f2bf(leakyf(u1.x + v1.x + c1.x));
        a[5] = (short)f2bf(leakyf(u1.y + v1.y + c1.y));
        a[6] = (short)f2bf(leakyf(u1.z + v1.z + c1.z));
        a[7] = (short)f2bf(leakyf(u1.w + v1.w + c1.w));

        f32x4 A0 = {0.f, 0.f, 0.f, 0.f};
        f32x4 A1 = {0.f, 0.f, 0.f, 0.f};
        A0 = __builtin_amdgcn_mfma_f32_16x16x32_bf16(a, bfr0, A0, 0, 0, 0);
        A1 = __builtin_amdgcn_mfma_f32_16x16x32_bf16(a, bfr1, A1, 0, 0, 0);

        const int rowb = tt * 16 + kb * 4;
#pragma unroll
        for (int t = 0; t < 4; ++t) {
            h2w[(rowb + t) * 33 + lr]      = A0[t];
            h2w[(rowb + t) * 33 + 16 + lr] = A1[t];
        }
    }

    float mu_acc = mu_b[0] + 1e-10f;
    float sg = sig_b[0];
    const float* myrow = &h2w[lane * 33];
#pragma unroll
    for (int l = 0; l < 32; ++l) {
        float h = myrow[l] + b2[l];
        h = h > 0.f ? h : 0.01f * h;
        mu_acc += h * muW[l];
        sg     += h * sigW[l];
    }
    const int g2 = blockIdx.x * 256 + wv * 64 + lane;
    out[g2]         = softplusf(mu_acc);
    out[NPAIR + g2] = expf(fminf(fmaxf(sg, -20.f), 2.f));
    __syncthreads();
    asm volatile("" ::: "memory");
    }   // rep
}

// ---------------------------------------------------------------------------
// launch
// ---------------------------------------------------------------------------
extern "C" void kernel_launch(void* const* d_in, const int* in_sizes, int n_in,
                              void* d_out, int out_size, void* d_ws, size_t ws_size,
                              hipStream_t stream)
{
    const float* state  = (const float*)d_in[0];
    const float* conv_W = (const float*)d_in[1];
    const float* conv_b = (const float*)d_in[2];
    const float* lin1_W = (const float*)d_in[3];
    const float* lin1_b = (const float*)d_in[4];
    const float* lin2_W = (const float*)d_in[5];
    const float* lin2_b = (const float*)d_in[6];
    const float* mu_W   = (const float*)d_in[7];
    const float* mu_b   = (const float*)d_in[8];
    const float* sig_W  = (const float*)d_in[9];
    const float* sig_b  = (const float*)d_in[10];
    const int*   eidx   = (const int*)d_in[11];
    const int* e_src = eidx;
    const int* e_dst = eidx + NEDGE;

    float* out = (float*)d_out;

    // workspace layout
    char* wsb = (char*)d_ws;
    unsigned short* y = (unsigned short*)wsb;                 // (N+1)*128 bf16
    char* p = wsb + (size_t)(NNODE + 1) * NC * sizeof(unsigned short);
    float* x = (float*)p;            p += (size_t)NNODE * NC * sizeof(float);
    int* cnt = (int*)p;              p += (size_t)NNODE * sizeof(int);
    int* bucket = (int*)p;           p += (size_t)NNODE * BCAP * sizeof(int);
    unsigned short* convWt = (unsigned short*)p;  p += 128 * 128 * sizeof(unsigned short);
    unsigned short* Whi = (unsigned short*)p;     p += 64 * 128 * sizeof(unsigned short);
    unsigned short* Wlo = (unsigned short*)p;     p += 64 * 128 * sizeof(unsigned short);
    unsigned short* W2cm = (unsigned short*)p;    p += 1024 * sizeof(unsigned short);
    float* uvb = (float*)p;          // N*64 f32

    init_misc<<<(NNODE + 255) / 256, 256, 0, stream>>>(
        cnt, y + (size_t)NNODE * NC, conv_W, convWt, lin1_W, Whi, Wlo,
        lin2_W, W2cm);

    bucket_fill<<<NEDGE / 256, 256, 0, stream>>>(e_src, e_dst, cnt, bucket);

    gemm1_mfma<<<NNODE / 128, 256, 0, stream>>>(state, convWt, cnt, y);

    gather_agg<<<(NNODE * 32) / 256, 256, 0, stream>>>(
        bucket, cnt, y, conv_b, state, x);

    gemm2_mfma<<<NNODE / 64, 256, 0, stream>>>(x, Whi, Wlo, uvb);

    pairs_mfma5_kernel<<<NPAIR / 256, 256, 0, stream>>>(
        uvb, W2cm, lin1_b, lin2_b, mu_W, mu_b, sig_W, sig_b, out);
}

// Round 19
// 77.172 us; speedup vs baseline: 4.8664x; 4.8664x over previous
//
#include <hip/hip_runtime.h>
#include <hip/hip_bf16.h>
#include <math.h>

// Problem constants
#define NB    2048          // B
#define ACT   14
#define NC    128           // C
#define NH    32            // H
#define NNODE (NB*ACT)      // 28672
#define NEDGE (NB*ACT*ACT)  // 401408
#define NPAIR (NB*ACT*ACT)  // 401408 output rows (b, 196)
#define BCAP  64            // bucket capacity per node (Poisson(14), P(>64)~1e-22)

typedef __attribute__((ext_vector_type(8))) short bf16x8;
typedef __attribute__((ext_vector_type(4))) float f32x4;

// bf16 helpers (RNE pack, cheap unpack)
__device__ __forceinline__ unsigned short f2bf(float f)
{
    unsigned u = __float_as_uint(f);
    return (unsigned short)((u + 0x7fff + ((u >> 16) & 1)) >> 16);
}
__device__ __forceinline__ float bf2f(unsigned short h)
{
    return __uint_as_float(((unsigned)h) << 16);
}
__device__ __forceinline__ float bfl(unsigned v) { return __uint_as_float(v << 16); }
__device__ __forceinline__ float bfh(unsigned v) { return __uint_as_float(v & 0xffff0000u); }

// ---------------------------------------------------------------------------
// init: cnt=0, dummy y row=0, pack convW^T bf16, pack W1 hi/lo bf16,
// pack W2 col-major bf16
// ---------------------------------------------------------------------------
__global__ __launch_bounds__(256) void init_misc(
    int* __restrict__ cnt, unsigned short* __restrict__ ydummy,
    const float* __restrict__ convW, unsigned short* __restrict__ convWt,
    const float* __restrict__ W1,
    unsigned short* __restrict__ Whi, unsigned short* __restrict__ Wlo,
    const float* __restrict__ W2, unsigned short* __restrict__ W2cm)
{
    int idx = blockIdx.x * 256 + threadIdx.x;          // 0 .. 28671
    if (idx < NNODE) cnt[idx] = 0;
    if (idx < 128) ydummy[idx] = 0;
    if (idx < 128 * 128) {                             // convWt[c][k] = convW[k][c]
        int c = idx >> 7, k = idx & 127;
        convWt[idx] = f2bf(convW[k * 128 + c]);
    }
    if (idx < 64 * 128) {                              // W1 packed col-major hi/lo
        int c = idx >> 7, k = idx & 127;
        float w = (c < 32) ? W1[k * 32 + c] : W1[(128 + k) * 32 + (c - 32)];
        unsigned short h = f2bf(w);
        Whi[idx] = h;
        Wlo[idx] = f2bf(w - bf2f(h));
    }
    if (idx < 1024) {                                  // W2cm[c][k] = W2[k][c]
        int c = idx >> 5, kk = idx & 31;
        W2cm[c * 32 + kk] = f2bf(W2[kk * 32 + c]);
    }
}

// ---------------------------------------------------------------------------
// bucket fill: slot = cnt[dst]++; bucket[dst*64+slot] = src   (int atomics)
// ---------------------------------------------------------------------------
__global__ void bucket_fill(const int* __restrict__ src, const int* __restrict__ dst,
                            int* __restrict__ cnt, int* __restrict__ bucket)
{
    int e = blockIdx.x * blockDim.x + threadIdx.x;
    if (e < NEDGE) {
        int d = dst[e];
        int slot = atomicAdd(&cnt[d], 1);
        if (slot < BCAP) bucket[(size_t)d * BCAP + slot] = src[e];
    }
}

// ---------------------------------------------------------------------------
// GEMM1 (MFMA, split-precision A): y = (state @ convW) * rsqrt(cnt+1), bf16 out.
// ---------------------------------------------------------------------------
__global__ __launch_bounds__(256) void gemm1_mfma(
    const float* __restrict__ A, const unsigned short* __restrict__ Bt,
    const int* __restrict__ cnt, unsigned short* __restrict__ y)
{
    __shared__ unsigned short Ah[128 * 128];   // 32 KB
    __shared__ unsigned short Alo[128 * 128];  // 32 KB
    __shared__ unsigned short Bl[128 * 128];   // 32 KB
    const int tid  = threadIdx.x;
    const int row0 = blockIdx.x * 128;

#pragma unroll
    for (int it = 0; it < 16; ++it) {
        int idx = tid + it * 256;
        int r = idx >> 5;
        int c = (idx & 31) << 2;
        float4 v = ((const float4*)(A + (size_t)(row0 + r) * 128))[idx & 31];
        ushort4 h, l;
        h.x = f2bf(v.x); l.x = f2bf(v.x - bf2f(h.x));
        h.y = f2bf(v.y); l.y = f2bf(v.y - bf2f(h.y));
        h.z = f2bf(v.z); l.z = f2bf(v.z - bf2f(h.z));
        h.w = f2bf(v.w); l.w = f2bf(v.w - bf2f(h.w));
        int byte = (r * 256 + c * 2) ^ ((r & 7) << 4);
        *(ushort4*)((char*)Ah  + byte) = h;
        *(ushort4*)((char*)Alo + byte) = l;
    }
#pragma unroll
    for (int it = 0; it < 8; ++it) {
        int idx = tid + it * 256;
        int cc = idx >> 4;                     // 0..127
        int kk = (idx & 15) << 3;              // 0..120
        bf16x8 v = *((const bf16x8*)(Bt + cc * 128 + kk));
        int byte = (cc * 256 + kk * 2) ^ ((cc & 7) << 4);
        *(bf16x8*)((char*)Bl + byte) = v;
    }
    __syncthreads();

    const int wv = tid >> 6, lane = tid & 63;
    const int lr = lane & 15, kb = lane >> 4;
    const int col0 = wv * 32;

    f32x4 acc0[8], acc1[8];
#pragma unroll
    for (int mt = 0; mt < 8; ++mt) {
        acc0[mt] = (f32x4){0.f, 0.f, 0.f, 0.f};
        acc1[mt] = (f32x4){0.f, 0.f, 0.f, 0.f};
    }

#pragma unroll
    for (int ks = 0; ks < 4; ++ks) {
        const int kbyte = (ks * 32 + kb * 8) * 2;
        int cb0 = ((col0 + lr) * 256 + kbyte) ^ (((col0 + lr) & 7) << 4);
        int cb1 = ((col0 + 16 + lr) * 256 + kbyte) ^ (((col0 + 16 + lr) & 7) << 4);
        bf16x8 b0 = *(const bf16x8*)((char*)Bl + cb0);
        bf16x8 b1 = *(const bf16x8*)((char*)Bl + cb1);
#pragma unroll
        for (int mt = 0; mt < 8; ++mt) {
            int rr = mt * 16 + lr;
            int ab = (rr * 256 + kbyte) ^ ((rr & 7) << 4);
            bf16x8 ah = *(const bf16x8*)((char*)Ah  + ab);
            bf16x8 al = *(const bf16x8*)((char*)Alo + ab);
            acc0[mt] = __builtin_amdgcn_mfma_f32_16x16x32_bf16(ah, b0, acc0[mt], 0, 0, 0);
            acc0[mt] = __builtin_amdgcn_mfma_f32_16x16x32_bf16(al, b0, acc0[mt], 0, 0, 0);
            acc1[mt] = __builtin_amdgcn_mfma_f32_16x16x32_bf16(ah, b1, acc1[mt], 0, 0, 0);
            acc1[mt] = __builtin_amdgcn_mfma_f32_16x16x32_bf16(al, b1, acc1[mt], 0, 0, 0);
        }
    }

#pragma unroll
    for (int mt = 0; mt < 8; ++mt) {
#pragma unroll
        for (int t = 0; t < 4; ++t) {
            int grow = row0 + mt * 16 + kb * 4 + t;
            float s = rsqrtf((float)cnt[grow] + 1.0f);
            y[(size_t)grow * 128 + col0 + lr]      = f2bf(acc0[mt][t] * s);
            y[(size_t)grow * 128 + col0 + 16 + lr] = f2bf(acc1[mt][t] * s);
        }
    }
}

// ---------------------------------------------------------------------------
// GEMM2 (MFMA split-precision both sides): uv = x @ W1p, fp32-accurate.
// ---------------------------------------------------------------------------
__global__ __launch_bounds__(256) void gemm2_mfma(
    const float* __restrict__ X, const unsigned short* __restrict__ Whi,
    const unsigned short* __restrict__ Wlo, float* __restrict__ U)
{
    __shared__ unsigned short Ah[64 * 128];    // 16 KB
    __shared__ unsigned short Alo[64 * 128];   // 16 KB
    __shared__ unsigned short Bh[64 * 128];    // 16 KB
    __shared__ unsigned short Blo[64 * 128];   // 16 KB
    const int tid  = threadIdx.x;
    const int row0 = blockIdx.x * 64;

#pragma unroll
    for (int it = 0; it < 8; ++it) {
        int idx = tid + it * 256;
        int r = idx >> 5;
        int c = (idx & 31) << 2;
        float4 v = ((const float4*)(X + (size_t)(row0 + r) * 128))[idx & 31];
        ushort4 h, l;
        h.x = f2bf(v.x); l.x = f2bf(v.x - bf2f(h.x));
        h.y = f2bf(v.y); l.y = f2bf(v.y - bf2f(h.y));
        h.z = f2bf(v.z); l.z = f2bf(v.z - bf2f(h.z));
        h.w = f2bf(v.w); l.w = f2bf(v.w - bf2f(h.w));
        int byte = (r * 256 + c * 2) ^ ((r & 7) << 4);
        *(ushort4*)((char*)Ah  + byte) = h;
        *(ushort4*)((char*)Alo + byte) = l;
    }
#pragma unroll
    for (int it = 0; it < 4; ++it) {
        int idx = tid + it * 256;
        int cc = idx >> 4;                     // 0..63
        int kk = (idx & 15) << 3;              // 0..120
        int byte = (cc * 256 + kk * 2) ^ ((cc & 7) << 4);
        *(bf16x8*)((char*)Bh  + byte) = *((const bf16x8*)(Whi + cc * 128 + kk));
        *(bf16x8*)((char*)Blo + byte) = *((const bf16x8*)(Wlo + cc * 128 + kk));
    }
    __syncthreads();

    const int wv = tid >> 6, lane = tid & 63;
    const int lr = lane & 15, kb = lane >> 4;
    const int col0 = wv * 16;

    f32x4 acc[4];
#pragma unroll
    for (int mt = 0; mt < 4; ++mt) acc[mt] = (f32x4){0.f, 0.f, 0.f, 0.f};

#pragma unroll
    for (int ks = 0; ks < 4; ++ks) {
        const int kbyte = (ks * 32 + kb * 8) * 2;
        int cb = ((col0 + lr) * 256 + kbyte) ^ (((col0 + lr) & 7) << 4);
        bf16x8 bh = *(const bf16x8*)((char*)Bh  + cb);
        bf16x8 bl = *(const bf16x8*)((char*)Blo + cb);
#pragma unroll
        for (int mt = 0; mt < 4; ++mt) {
            int rr = mt * 16 + lr;
            int ab = (rr * 256 + kbyte) ^ ((rr & 7) << 4);
            bf16x8 ah = *(const bf16x8*)((char*)Ah  + ab);
            bf16x8 al = *(const bf16x8*)((char*)Alo + ab);
            acc[mt] = __builtin_amdgcn_mfma_f32_16x16x32_bf16(ah, bh, acc[mt], 0, 0, 0);
            acc[mt] = __builtin_amdgcn_mfma_f32_16x16x32_bf16(al, bh, acc[mt], 0, 0, 0);
            acc[mt] = __builtin_amdgcn_mfma_f32_16x16x32_bf16(ah, bl, acc[mt], 0, 0, 0);
        }
    }

#pragma unroll
    for (int mt = 0; mt < 4; ++mt) {
#pragma unroll
        for (int t = 0; t < 4; ++t) {
            int grow = row0 + mt * 16 + kb * 4 + t;
            U[(size_t)grow * 64 + col0 + lr] = acc[mt][t];
        }
    }
}

// ---------------------------------------------------------------------------
// gather aggregation + GCN epilogue (bf16 y rows) -- R14 version (best)
// ---------------------------------------------------------------------------
__global__ __launch_bounds__(256) void gather_agg(
    const int* __restrict__ bucket, const int* __restrict__ cnt,
    const unsigned short* __restrict__ y, const float* __restrict__ bias,
    const float* __restrict__ state, float* __restrict__ xout)
{
    const int lane = threadIdx.x & 31;
    const int d = (blockIdx.x * 256 + threadIdx.x) >> 5;   // node id
    if (d >= NNODE) return;

    const int c_true = cnt[d];
    const int c = c_true < BCAP ? c_true : BCAP;

    uint2 sv0 = ((const uint2*)(y + (size_t)d * NC))[lane];  // self loop
    float4 acc;
    acc.x = bfl(sv0.x); acc.y = bfh(sv0.x);
    acc.z = bfl(sv0.y); acc.w = bfh(sv0.y);

    const int* brow = bucket + (size_t)d * BCAP;
    for (int base = 0; base < c; base += 32) {
        int rem = c - base;
        int m = rem < 32 ? rem : 32;
        int sv = (lane < m) ? brow[base + lane] : NNODE;   // zero row
        int mm = (m + 3) & ~3;
        for (int j = 0; j < mm; j += 4) {
            int s0 = __shfl(sv, j + 0, 32);
            int s1 = __shfl(sv, j + 1, 32);
            int s2 = __shfl(sv, j + 2, 32);
            int s3 = __shfl(sv, j + 3, 32);
            uint2 a0 = ((const uint2*)(y + (size_t)s0 * NC))[lane];
            uint2 a1 = ((const uint2*)(y + (size_t)s1 * NC))[lane];
            uint2 a2 = ((const uint2*)(y + (size_t)s2 * NC))[lane];
            uint2 a3 = ((const uint2*)(y + (size_t)s3 * NC))[lane];
            acc.x += bfl(a0.x) + bfl(a1.x) + bfl(a2.x) + bfl(a3.x);
            acc.y += bfh(a0.x) + bfh(a1.x) + bfh(a2.x) + bfh(a3.x);
            acc.z += bfl(a0.y) + bfl(a1.y) + bfl(a2.y) + bfl(a3.y);
            acc.w += bfh(a0.y) + bfh(a1.y) + bfh(a2.y) + bfh(a3.y);
        }
    }

    const float dv = rsqrtf((float)c_true + 1.0f);
    float4 b  = ((const float4*)bias)[lane];
    float4 st = ((const float4*)(state + (size_t)d * NC))[lane];
    float4 r;
    r.x = fmaxf(acc.x * dv + b.x, 0.f) + st.x;
    r.y = fmaxf(acc.y * dv + b.y, 0.f) + st.y;
    r.z = fmaxf(acc.z * dv + b.z, 0.f) + st.z;
    r.w = fmaxf(acc.w * dv + b.w, 0.f) + st.w;
    ((float4*)(xout + (size_t)d * NC))[lane] = r;
}

// ---------------------------------------------------------------------------
// pairs v7 = R14 v6 with the two counter-driven fixes:
//  - NO uvs LDS staging: uv is L2-resident (7.3 MB); direct global reads.
//    LDS 45.5 -> 35 KB => 4 blocks/CU (occupancy 26 -> ~40%).
//  - h2s row stride 33 -> 35 (35==3 mod 32): h2 writes (rows 4 apart across
//    kb quarters) become <=2-way, epilogue reads stay 2-way; kills the
//    577K/run SQ_LDS_BANK_CONFLICT cycles measured in R18.
// ---------------------------------------------------------------------------
__device__ __forceinline__ float softplusf(float z)
{
    return z > 0.f ? z + log1pf(expf(-z)) : log1pf(expf(z));
}
__device__ __forceinline__ float leakyf(float z)
{
    return z > 0.f ? z : 0.01f * z;
}

__global__ __launch_bounds__(256) void pairs_mfma7_kernel(
    const float* __restrict__ uv, const unsigned short* __restrict__ W2cm,
    const float* __restrict__ b1, const float* __restrict__ b2,
    const float* __restrict__ muW, const float* __restrict__ mu_b,
    const float* __restrict__ sigW, const float* __restrict__ sig_b,
    float* __restrict__ out)
{
    __shared__ float h2s[4][64 * 35];      // 35 KB
    const int tid  = threadIdx.x;
    const int wv   = tid >> 6;
    const int lane = tid & 63;
    const int lr   = lane & 15;            // A row-in-tile / D unit col
    const int kb   = lane >> 4;            // k-block / D pair-row group
    const int k0   = kb * 8;

    // wave-invariant: B-frags (W2 cols), b1 k-slice
    bf16x8 bfr0 = *((const bf16x8*)(W2cm + (size_t)lr * 32 + k0));        // units 0-15
    bf16x8 bfr1 = *((const bf16x8*)(W2cm + (size_t)(16 + lr) * 32 + k0)); // units 16-31
    float4 c0 = *((const float4*)(b1 + k0));
    float4 c1 = *((const float4*)(b1 + k0 + 4));

    float* h2w = h2s[wv];
#pragma unroll
    for (int tt = 0; tt < 4; ++tt) {
        const int g = blockIdx.x * 256 + wv * 64 + tt * 16 + lr;   // pair id
        const int b = g / 196;
        const int p = g - b * 196;
        const int i = p / 14;
        const int j = p - i * 14;
        const float* up = uv + (size_t)(b * ACT + i) * 64 + k0;
        const float* vp = uv + (size_t)(b * ACT + j) * 64 + 32 + k0;
        float4 u0 = *((const float4*)up);
        float4 u1 = *((const float4*)(up + 4));
        float4 v0 = *((const float4*)vp);
        float4 v1 = *((const float4*)(vp + 4));

        bf16x8 a;
        a[0] = (short)f2bf(leakyf(u0.x + v0.x + c0.x));
        a[1] = (short)f2bf(leakyf(u0.y + v0.y + c0.y));
        a[2] = (short)f2bf(leakyf(u0.z + v0.z + c0.z));
        a[3] = (short)f2bf(leakyf(u0.w + v0.w + c0.w));
        a[4] = (short)f2bf(leakyf(u1.x + v1.x + c1.x));
        a[5] = (short)f2bf(leakyf(u1.y + v1.y + c1.y));
        a[6] = (short)f2bf(leakyf(u1.z + v1.z + c1.z));
        a[7] = (short)f2bf(leakyf(u1.w + v1.w + c1.w));

        f32x4 A0 = {0.f, 0.f, 0.f, 0.f};
        f32x4 A1 = {0.f, 0.f, 0.f, 0.f};
        A0 = __builtin_amdgcn_mfma_f32_16x16x32_bf16(a, bfr0, A0, 0, 0, 0);
        A1 = __builtin_amdgcn_mfma_f32_16x16x32_bf16(a, bfr1, A1, 0, 0, 0);

        const int rowb = tt * 16 + kb * 4;
#pragma unroll
        for (int t = 0; t < 4; ++t) {
            h2w[(rowb + t) * 35 + lr]      = A0[t];
            h2w[(rowb + t) * 35 + 16 + lr] = A1[t];
        }
    }

    // wave-local epilogue: lane finishes pair (wv*64 + lane).
    float mu_acc = mu_b[0] + 1e-10f;
    float sg = sig_b[0];
    const float* myrow = &h2w[lane * 35];
#pragma unroll
    for (int l = 0; l < 32; ++l) {
        float h = myrow[l] + b2[l];        // b2/muW/sigW uniform -> s_load
        h = h > 0.f ? h : 0.01f * h;
        mu_acc += h * muW[l];
        sg     += h * sigW[l];
    }
    const int g2 = blockIdx.x * 256 + wv * 64 + lane;
    out[g2]         = softplusf(mu_acc);
    out[NPAIR + g2] = expf(fminf(fmaxf(sg, -20.f), 2.f));
}

// ---------------------------------------------------------------------------
// launch
// ---------------------------------------------------------------------------
extern "C" void kernel_launch(void* const* d_in, const int* in_sizes, int n_in,
                              void* d_out, int out_size, void* d_ws, size_t ws_size,
                              hipStream_t stream)
{
    const float* state  = (const float*)d_in[0];
    const float* conv_W = (const float*)d_in[1];
    const float* conv_b = (const float*)d_in[2];
    const float* lin1_W = (const float*)d_in[3];
    const float* lin1_b = (const float*)d_in[4];
    const float* lin2_W = (const float*)d_in[5];
    const float* lin2_b = (const float*)d_in[6];
    const float* mu_W   = (const float*)d_in[7];
    const float* mu_b   = (const float*)d_in[8];
    const float* sig_W  = (const float*)d_in[9];
    const float* sig_b  = (const float*)d_in[10];
    const int*   eidx   = (const int*)d_in[11];
    const int* e_src = eidx;
    const int* e_dst = eidx + NEDGE;

    float* out = (float*)d_out;

    // workspace layout
    char* wsb = (char*)d_ws;
    unsigned short* y = (unsigned short*)wsb;                 // (N+1)*128 bf16
    char* p = wsb + (size_t)(NNODE + 1) * NC * sizeof(unsigned short);
    float* x = (float*)p;            p += (size_t)NNODE * NC * sizeof(float);
    int* cnt = (int*)p;              p += (size_t)NNODE * sizeof(int);
    int* bucket = (int*)p;           p += (size_t)NNODE * BCAP * sizeof(int);
    unsigned short* convWt = (unsigned short*)p;  p += 128 * 128 * sizeof(unsigned short);
    unsigned short* Whi = (unsigned short*)p;     p += 64 * 128 * sizeof(unsigned short);
    unsigned short* Wlo = (unsigned short*)p;     p += 64 * 128 * sizeof(unsigned short);
    unsigned short* W2cm = (unsigned short*)p;    p += 1024 * sizeof(unsigned short);
    float* uvb = (float*)p;          // N*64 f32

    // init: cnt=0, y dummy row=0, convWt bf16, W1 hi/lo bf16, W2 col-major bf16
    init_misc<<<(NNODE + 255) / 256, 256, 0, stream>>>(
        cnt, y + (size_t)NNODE * NC, conv_W, convWt, lin1_W, Whi, Wlo,
        lin2_W, W2cm);

    // bucket CSR (no scan)
    bucket_fill<<<NEDGE / 256, 256, 0, stream>>>(e_src, e_dst, cnt, bucket);

    // y = (state @ conv_W) * rsqrt(cnt+1)   [MFMA, split-precision A]
    gemm1_mfma<<<NNODE / 128, 256, 0, stream>>>(state, convWt, cnt, y);

    // x = relu(dinv*(y_self + sum y[src]) + b) + state
    gather_agg<<<(NNODE * 32) / 256, 256, 0, stream>>>(
        bucket, cnt, y, conv_b, state, x);

    // uv = x @ [W1_top | W1_bot]   [MFMA split-precision]
    gemm2_mfma<<<NNODE / 64, 256, 0, stream>>>(x, Whi, Wlo, uvb);

    // pairs -> output (v7: no uvs staging, stride-35 h2s)
    pairs_mfma7_kernel<<<NPAIR / 256, 256, 0, stream>>>(
        uvb, W2cm, lin1_b, lin2_b, mu_W, mu_b, sig_W, sig_b, out);
}

// Round 20
// 76.716 us; speedup vs baseline: 4.8953x; 1.0060x over previous
//
#include <hip/hip_runtime.h>
#include <hip/hip_bf16.h>
#include <math.h>

// Problem constants
#define NB    2048          // B
#define ACT   14
#define NC    128           // C
#define NH    32            // H
#define NNODE (NB*ACT)      // 28672
#define NEDGE (NB*ACT*ACT)  // 401408
#define NPAIR (NB*ACT*ACT)  // 401408 output rows (b, 196)
#define BCAP  64            // bucket capacity per node (Poisson(14), P(>64)~1e-22)

typedef __attribute__((ext_vector_type(8))) short bf16x8;
typedef __attribute__((ext_vector_type(4))) float f32x4;

// bf16 helpers — NATIVE conversion (compiler pairs casts into v_cvt_pk_bf16_f32;
// manual RNE bit-twiddle was ~4-5 VALU ops each and made pairs VALU-bound, R18)
__device__ __forceinline__ unsigned short f2bf(float f)
{
    __hip_bfloat16 h = __float2bfloat16(f);      // RNE, same as old emulation
    return *reinterpret_cast<unsigned short*>(&h);
}
__device__ __forceinline__ float bf2f(unsigned short h)
{
    return __uint_as_float(((unsigned)h) << 16);
}
__device__ __forceinline__ float bfl(unsigned v) { return __uint_as_float(v << 16); }
__device__ __forceinline__ float bfh(unsigned v) { return __uint_as_float(v & 0xffff0000u); }

// ---------------------------------------------------------------------------
// init: cnt=0, dummy y row=0, pack convW^T bf16, pack W1 hi/lo bf16,
// pack W2 col-major bf16
// ---------------------------------------------------------------------------
__global__ __launch_bounds__(256) void init_misc(
    int* __restrict__ cnt, unsigned short* __restrict__ ydummy,
    const float* __restrict__ convW, unsigned short* __restrict__ convWt,
    const float* __restrict__ W1,
    unsigned short* __restrict__ Whi, unsigned short* __restrict__ Wlo,
    const float* __restrict__ W2, unsigned short* __restrict__ W2cm)
{
    int idx = blockIdx.x * 256 + threadIdx.x;          // 0 .. 28671
    if (idx < NNODE) cnt[idx] = 0;
    if (idx < 128) ydummy[idx] = 0;
    if (idx < 128 * 128) {                             // convWt[c][k] = convW[k][c]
        int c = idx >> 7, k = idx & 127;
        convWt[idx] = f2bf(convW[k * 128 + c]);
    }
    if (idx < 64 * 128) {                              // W1 packed col-major hi/lo
        int c = idx >> 7, k = idx & 127;
        float w = (c < 32) ? W1[k * 32 + c] : W1[(128 + k) * 32 + (c - 32)];
        unsigned short h = f2bf(w);
        Whi[idx] = h;
        Wlo[idx] = f2bf(w - bf2f(h));
    }
    if (idx < 1024) {                                  // W2cm[c][k] = W2[k][c]
        int c = idx >> 5, kk = idx & 31;
        W2cm[c * 32 + kk] = f2bf(W2[kk * 32 + c]);
    }
}

// ---------------------------------------------------------------------------
// bucket fill: slot = cnt[dst]++; bucket[dst*64+slot] = src   (int atomics)
// ---------------------------------------------------------------------------
__global__ void bucket_fill(const int* __restrict__ src, const int* __restrict__ dst,
                            int* __restrict__ cnt, int* __restrict__ bucket)
{
    int e = blockIdx.x * blockDim.x + threadIdx.x;
    if (e < NEDGE) {
        int d = dst[e];
        int slot = atomicAdd(&cnt[d], 1);
        if (slot < BCAP) bucket[(size_t)d * BCAP + slot] = src[e];
    }
}

// ---------------------------------------------------------------------------
// GEMM1 (MFMA, split-precision A): y = (state @ convW) * rsqrt(cnt+1), bf16 out.
// ---------------------------------------------------------------------------
__global__ __launch_bounds__(256) void gemm1_mfma(
    const float* __restrict__ A, const unsigned short* __restrict__ Bt,
    const int* __restrict__ cnt, unsigned short* __restrict__ y)
{
    __shared__ unsigned short Ah[128 * 128];   // 32 KB
    __shared__ unsigned short Alo[128 * 128];  // 32 KB
    __shared__ unsigned short Bl[128 * 128];   // 32 KB
    const int tid  = threadIdx.x;
    const int row0 = blockIdx.x * 128;

#pragma unroll
    for (int it = 0; it < 16; ++it) {
        int idx = tid + it * 256;
        int r = idx >> 5;
        int c = (idx & 31) << 2;
        float4 v = ((const float4*)(A + (size_t)(row0 + r) * 128))[idx & 31];
        ushort4 h, l;
        h.x = f2bf(v.x); l.x = f2bf(v.x - bf2f(h.x));
        h.y = f2bf(v.y); l.y = f2bf(v.y - bf2f(h.y));
        h.z = f2bf(v.z); l.z = f2bf(v.z - bf2f(h.z));
        h.w = f2bf(v.w); l.w = f2bf(v.w - bf2f(h.w));
        int byte = (r * 256 + c * 2) ^ ((r & 7) << 4);
        *(ushort4*)((char*)Ah  + byte) = h;
        *(ushort4*)((char*)Alo + byte) = l;
    }
#pragma unroll
    for (int it = 0; it < 8; ++it) {
        int idx = tid + it * 256;
        int cc = idx >> 4;                     // 0..127
        int kk = (idx & 15) << 3;              // 0..120
        bf16x8 v = *((const bf16x8*)(Bt + cc * 128 + kk));
        int byte = (cc * 256 + kk * 2) ^ ((cc & 7) << 4);
        *(bf16x8*)((char*)Bl + byte) = v;
    }
    __syncthreads();

    const int wv = tid >> 6, lane = tid & 63;
    const int lr = lane & 15, kb = lane >> 4;
    const int col0 = wv * 32;

    f32x4 acc0[8], acc1[8];
#pragma unroll
    for (int mt = 0; mt < 8; ++mt) {
        acc0[mt] = (f32x4){0.f, 0.f, 0.f, 0.f};
        acc1[mt] = (f32x4){0.f, 0.f, 0.f, 0.f};
    }

#pragma unroll
    for (int ks = 0; ks < 4; ++ks) {
        const int kbyte = (ks * 32 + kb * 8) * 2;
        int cb0 = ((col0 + lr) * 256 + kbyte) ^ (((col0 + lr) & 7) << 4);
        int cb1 = ((col0 + 16 + lr) * 256 + kbyte) ^ (((col0 + 16 + lr) & 7) << 4);
        bf16x8 b0 = *(const bf16x8*)((char*)Bl + cb0);
        bf16x8 b1 = *(const bf16x8*)((char*)Bl + cb1);
#pragma unroll
        for (int mt = 0; mt < 8; ++mt) {
            int rr = mt * 16 + lr;
            int ab = (rr * 256 + kbyte) ^ ((rr & 7) << 4);
            bf16x8 ah = *(const bf16x8*)((char*)Ah  + ab);
            bf16x8 al = *(const bf16x8*)((char*)Alo + ab);
            acc0[mt] = __builtin_amdgcn_mfma_f32_16x16x32_bf16(ah, b0, acc0[mt], 0, 0, 0);
            acc0[mt] = __builtin_amdgcn_mfma_f32_16x16x32_bf16(al, b0, acc0[mt], 0, 0, 0);
            acc1[mt] = __builtin_amdgcn_mfma_f32_16x16x32_bf16(ah, b1, acc1[mt], 0, 0, 0);
            acc1[mt] = __builtin_amdgcn_mfma_f32_16x16x32_bf16(al, b1, acc1[mt], 0, 0, 0);
        }
    }

#pragma unroll
    for (int mt = 0; mt < 8; ++mt) {
#pragma unroll
        for (int t = 0; t < 4; ++t) {
            int grow = row0 + mt * 16 + kb * 4 + t;
            float s = rsqrtf((float)cnt[grow] + 1.0f);
            y[(size_t)grow * 128 + col0 + lr]      = f2bf(acc0[mt][t] * s);
            y[(size_t)grow * 128 + col0 + 16 + lr] = f2bf(acc1[mt][t] * s);
        }
    }
}

// ---------------------------------------------------------------------------
// GEMM2 (MFMA split-precision both sides): uv = x @ W1p, fp32-accurate.
// ---------------------------------------------------------------------------
__global__ __launch_bounds__(256) void gemm2_mfma(
    const float* __restrict__ X, const unsigned short* __restrict__ Whi,
    const unsigned short* __restrict__ Wlo, float* __restrict__ U)
{
    __shared__ unsigned short Ah[64 * 128];    // 16 KB
    __shared__ unsigned short Alo[64 * 128];   // 16 KB
    __shared__ unsigned short Bh[64 * 128];    // 16 KB
    __shared__ unsigned short Blo[64 * 128];   // 16 KB
    const int tid  = threadIdx.x;
    const int row0 = blockIdx.x * 64;

#pragma unroll
    for (int it = 0; it < 8; ++it) {
        int idx = tid + it * 256;
        int r = idx >> 5;
        int c = (idx & 31) << 2;
        float4 v = ((const float4*)(X + (size_t)(row0 + r) * 128))[idx & 31];
        ushort4 h, l;
        h.x = f2bf(v.x); l.x = f2bf(v.x - bf2f(h.x));
        h.y = f2bf(v.y); l.y = f2bf(v.y - bf2f(h.y));
        h.z = f2bf(v.z); l.z = f2bf(v.z - bf2f(h.z));
        h.w = f2bf(v.w); l.w = f2bf(v.w - bf2f(h.w));
        int byte = (r * 256 + c * 2) ^ ((r & 7) << 4);
        *(ushort4*)((char*)Ah  + byte) = h;
        *(ushort4*)((char*)Alo + byte) = l;
    }
#pragma unroll
    for (int it = 0; it < 4; ++it) {
        int idx = tid + it * 256;
        int cc = idx >> 4;                     // 0..63
        int kk = (idx & 15) << 3;              // 0..120
        int byte = (cc * 256 + kk * 2) ^ ((cc & 7) << 4);
        *(bf16x8*)((char*)Bh  + byte) = *((const bf16x8*)(Whi + cc * 128 + kk));
        *(bf16x8*)((char*)Blo + byte) = *((const bf16x8*)(Wlo + cc * 128 + kk));
    }
    __syncthreads();

    const int wv = tid >> 6, lane = tid & 63;
    const int lr = lane & 15, kb = lane >> 4;
    const int col0 = wv * 16;

    f32x4 acc[4];
#pragma unroll
    for (int mt = 0; mt < 4; ++mt) acc[mt] = (f32x4){0.f, 0.f, 0.f, 0.f};

#pragma unroll
    for (int ks = 0; ks < 4; ++ks) {
        const int kbyte = (ks * 32 + kb * 8) * 2;
        int cb = ((col0 + lr) * 256 + kbyte) ^ (((col0 + lr) & 7) << 4);
        bf16x8 bh = *(const bf16x8*)((char*)Bh  + cb);
        bf16x8 bl = *(const bf16x8*)((char*)Blo + cb);
#pragma unroll
        for (int mt = 0; mt < 4; ++mt) {
            int rr = mt * 16 + lr;
            int ab = (rr * 256 + kbyte) ^ ((rr & 7) << 4);
            bf16x8 ah = *(const bf16x8*)((char*)Ah  + ab);
            bf16x8 al = *(const bf16x8*)((char*)Alo + ab);
            acc[mt] = __builtin_amdgcn_mfma_f32_16x16x32_bf16(ah, bh, acc[mt], 0, 0, 0);
            acc[mt] = __builtin_amdgcn_mfma_f32_16x16x32_bf16(al, bh, acc[mt], 0, 0, 0);
            acc[mt] = __builtin_amdgcn_mfma_f32_16x16x32_bf16(ah, bl, acc[mt], 0, 0, 0);
        }
    }

#pragma unroll
    for (int mt = 0; mt < 4; ++mt) {
#pragma unroll
        for (int t = 0; t < 4; ++t) {
            int grow = row0 + mt * 16 + kb * 4 + t;
            U[(size_t)grow * 64 + col0 + lr] = acc[mt][t];
        }
    }
}

// ---------------------------------------------------------------------------
// gather aggregation + GCN epilogue (bf16 y rows) -- R14 version (best)
// ---------------------------------------------------------------------------
__global__ __launch_bounds__(256) void gather_agg(
    const int* __restrict__ bucket, const int* __restrict__ cnt,
    const unsigned short* __restrict__ y, const float* __restrict__ bias,
    const float* __restrict__ state, float* __restrict__ xout)
{
    const int lane = threadIdx.x & 31;
    const int d = (blockIdx.x * 256 + threadIdx.x) >> 5;   // node id
    if (d >= NNODE) return;

    const int c_true = cnt[d];
    const int c = c_true < BCAP ? c_true : BCAP;

    uint2 sv0 = ((const uint2*)(y + (size_t)d * NC))[lane];  // self loop
    float4 acc;
    acc.x = bfl(sv0.x); acc.y = bfh(sv0.x);
    acc.z = bfl(sv0.y); acc.w = bfh(sv0.y);

    const int* brow = bucket + (size_t)d * BCAP;
    for (int base = 0; base < c; base += 32) {
        int rem = c - base;
        int m = rem < 32 ? rem : 32;
        int sv = (lane < m) ? brow[base + lane] : NNODE;   // zero row
        int mm = (m + 3) & ~3;
        for (int j = 0; j < mm; j += 4) {
            int s0 = __shfl(sv, j + 0, 32);
            int s1 = __shfl(sv, j + 1, 32);
            int s2 = __shfl(sv, j + 2, 32);
            int s3 = __shfl(sv, j + 3, 32);
            uint2 a0 = ((const uint2*)(y + (size_t)s0 * NC))[lane];
            uint2 a1 = ((const uint2*)(y + (size_t)s1 * NC))[lane];
            uint2 a2 = ((const uint2*)(y + (size_t)s2 * NC))[lane];
            uint2 a3 = ((const uint2*)(y + (size_t)s3 * NC))[lane];
            acc.x += bfl(a0.x) + bfl(a1.x) + bfl(a2.x) + bfl(a3.x);
            acc.y += bfh(a0.x) + bfh(a1.x) + bfh(a2.x) + bfh(a3.x);
            acc.z += bfl(a0.y) + bfl(a1.y) + bfl(a2.y) + bfl(a3.y);
            acc.w += bfh(a0.y) + bfh(a1.y) + bfh(a2.y) + bfh(a3.y);
        }
    }

    const float dv = rsqrtf((float)c_true + 1.0f);
    float4 b  = ((const float4*)bias)[lane];
    float4 st = ((const float4*)(state + (size_t)d * NC))[lane];
    float4 r;
    r.x = fmaxf(acc.x * dv + b.x, 0.f) + st.x;
    r.y = fmaxf(acc.y * dv + b.y, 0.f) + st.y;
    r.z = fmaxf(acc.z * dv + b.z, 0.f) + st.z;
    r.w = fmaxf(acc.w * dv + b.w, 0.f) + st.w;
    ((float4*)(xout + (size_t)d * NC))[lane] = r;
}

// ---------------------------------------------------------------------------
// pairs v8 = v7 + native bf16 conversions (v_cvt_pk_bf16_f32 via compiler).
// R18 showed pairs is VALU-issue-bound (VALUBusy 66%); the manual RNE
// emulation was ~half its VALU ops.
// ---------------------------------------------------------------------------
__device__ __forceinline__ float softplusf(float z)
{
    return z > 0.f ? z + log1pf(expf(-z)) : log1pf(expf(z));
}
__device__ __forceinline__ float leakyf(float z)
{
    return z > 0.f ? z : 0.01f * z;
}

__global__ __launch_bounds__(256) void pairs_mfma8_kernel(
    const float* __restrict__ uv, const unsigned short* __restrict__ W2cm,
    const float* __restrict__ b1, const float* __restrict__ b2,
    const float* __restrict__ muW, const float* __restrict__ mu_b,
    const float* __restrict__ sigW, const float* __restrict__ sig_b,
    float* __restrict__ out)
{
    __shared__ float h2s[4][64 * 35];      // 35 KB
    const int tid  = threadIdx.x;
    const int wv   = tid >> 6;
    const int lane = tid & 63;
    const int lr   = lane & 15;            // A row-in-tile / D unit col
    const int kb   = lane >> 4;            // k-block / D pair-row group
    const int k0   = kb * 8;

    // wave-invariant: B-frags (W2 cols), b1 k-slice
    bf16x8 bfr0 = *((const bf16x8*)(W2cm + (size_t)lr * 32 + k0));        // units 0-15
    bf16x8 bfr1 = *((const bf16x8*)(W2cm + (size_t)(16 + lr) * 32 + k0)); // units 16-31
    float4 c0 = *((const float4*)(b1 + k0));
    float4 c1 = *((const float4*)(b1 + k0 + 4));

    float* h2w = h2s[wv];
#pragma unroll
    for (int tt = 0; tt < 4; ++tt) {
        const int g = blockIdx.x * 256 + wv * 64 + tt * 16 + lr;   // pair id
        const int b = g / 196;
        const int p = g - b * 196;
        const int i = p / 14;
        const int j = p - i * 14;
        const float* up = uv + (size_t)(b * ACT + i) * 64 + k0;
        const float* vp = uv + (size_t)(b * ACT + j) * 64 + 32 + k0;
        float4 u0 = *((const float4*)up);
        float4 u1 = *((const float4*)(up + 4));
        float4 v0 = *((const float4*)vp);
        float4 v1 = *((const float4*)(vp + 4));

        bf16x8 a;
        a[0] = (short)f2bf(leakyf(u0.x + v0.x + c0.x));
        a[1] = (short)f2bf(leakyf(u0.y + v0.y + c0.y));
        a[2] = (short)f2bf(leakyf(u0.z + v0.z + c0.z));
        a[3] = (short)f2bf(leakyf(u0.w + v0.w + c0.w));
        a[4] = (short)f2bf(leakyf(u1.x + v1.x + c1.x));
        a[5] = (short)f2bf(leakyf(u1.y + v1.y + c1.y));
        a[6] = (short)f2bf(leakyf(u1.z + v1.z + c1.z));
        a[7] = (short)f2bf(leakyf(u1.w + v1.w + c1.w));

        f32x4 A0 = {0.f, 0.f, 0.f, 0.f};
        f32x4 A1 = {0.f, 0.f, 0.f, 0.f};
        A0 = __builtin_amdgcn_mfma_f32_16x16x32_bf16(a, bfr0, A0, 0, 0, 0);
        A1 = __builtin_amdgcn_mfma_f32_16x16x32_bf16(a, bfr1, A1, 0, 0, 0);

        const int rowb = tt * 16 + kb * 4;
#pragma unroll
        for (int t = 0; t < 4; ++t) {
            h2w[(rowb + t) * 35 + lr]      = A0[t];
            h2w[(rowb + t) * 35 + 16 + lr] = A1[t];
        }
    }

    // wave-local epilogue: lane finishes pair (wv*64 + lane).
    float mu_acc = mu_b[0] + 1e-10f;
    float sg = sig_b[0];
    const float* myrow = &h2w[lane * 35];
#pragma unroll
    for (int l = 0; l < 32; ++l) {
        float h = myrow[l] + b2[l];        // b2/muW/sigW uniform -> s_load
        h = h > 0.f ? h : 0.01f * h;
        mu_acc += h * muW[l];
        sg     += h * sigW[l];
    }
    const int g2 = blockIdx.x * 256 + wv * 64 + lane;
    out[g2]         = softplusf(mu_acc);
    out[NPAIR + g2] = expf(fminf(fmaxf(sg, -20.f), 2.f));
}

// ---------------------------------------------------------------------------
// launch
// ---------------------------------------------------------------------------
extern "C" void kernel_launch(void* const* d_in, const int* in_sizes, int n_in,
                              void* d_out, int out_size, void* d_ws, size_t ws_size,
                              hipStream_t stream)
{
    const float* state  = (const float*)d_in[0];
    const float* conv_W = (const float*)d_in[1];
    const float* conv_b = (const float*)d_in[2];
    const float* lin1_W = (const float*)d_in[3];
    const float* lin1_b = (const float*)d_in[4];
    const float* lin2_W = (const float*)d_in[5];
    const float* lin2_b = (const float*)d_in[6];
    const float* mu_W   = (const float*)d_in[7];
    const float* mu_b   = (const float*)d_in[8];
    const float* sig_W  = (const float*)d_in[9];
    const float* sig_b  = (const float*)d_in[10];
    const int*   eidx   = (const int*)d_in[11];
    const int* e_src = eidx;
    const int* e_dst = eidx + NEDGE;

    float* out = (float*)d_out;

    // workspace layout
    char* wsb = (char*)d_ws;
    unsigned short* y = (unsigned short*)wsb;                 // (N+1)*128 bf16
    char* p = wsb + (size_t)(NNODE + 1) * NC * sizeof(unsigned short);
    float* x = (float*)p;            p += (size_t)NNODE * NC * sizeof(float);
    int* cnt = (int*)p;              p += (size_t)NNODE * sizeof(int);
    int* bucket = (int*)p;           p += (size_t)NNODE * BCAP * sizeof(int);
    unsigned short* convWt = (unsigned short*)p;  p += 128 * 128 * sizeof(unsigned short);
    unsigned short* Whi = (unsigned short*)p;     p += 64 * 128 * sizeof(unsigned short);
    unsigned short* Wlo = (unsigned short*)p;     p += 64 * 128 * sizeof(unsigned short);
    unsigned short* W2cm = (unsigned short*)p;    p += 1024 * sizeof(unsigned short);
    float* uvb = (float*)p;          // N*64 f32

    // init: cnt=0, y dummy row=0, convWt bf16, W1 hi/lo bf16, W2 col-major bf16
    init_misc<<<(NNODE + 255) / 256, 256, 0, stream>>>(
        cnt, y + (size_t)NNODE * NC, conv_W, convWt, lin1_W, Whi, Wlo,
        lin2_W, W2cm);

    // bucket CSR (no scan)
    bucket_fill<<<NEDGE / 256, 256, 0, stream>>>(e_src, e_dst, cnt, bucket);

    // y = (state @ conv_W) * rsqrt(cnt+1)   [MFMA, split-precision A]
    gemm1_mfma<<<NNODE / 128, 256, 0, stream>>>(state, convWt, cnt, y);

    // x = relu(dinv*(y_self + sum y[src]) + b) + state
    gather_agg<<<(NNODE * 32) / 256, 256, 0, stream>>>(
        bucket, cnt, y, conv_b, state, x);

    // uv = x @ [W1_top | W1_bot]   [MFMA split-precision]
    gemm2_mfma<<<NNODE / 64, 256, 0, stream>>>(x, Whi, Wlo, uvb);

    // pairs -> output (v8: native cvt_pk conversions)
    pairs_mfma8_kernel<<<NPAIR / 256, 256, 0, stream>>>(
        uvb, W2cm, lin1_b, lin2_b, mu_W, mu_b, sig_W, sig_b, out);
}